// Round 4
// baseline (419.028 us; speedup 1.0000x reference)
//
#include <hip/hip_runtime.h>
#include <hip/hip_bf16.h>
#include <stdint.h>

// S5 layer: L=16384, H=1024, P=1024. Inputs AND output are fp32 (reference
// dtype; round-2/3 identical-absmax forensics showed the only shared bug was
// writing bf16 into the fp32 d_out). Internals use bf16 MFMA (m97 structure).
//
// Pipeline:
//   detect   : dtype flag (insurance; expect fp32 -> flag=1)
//   convert  : u fp32 -> ub bf16
//   prep     : lam, lam^64, W1t(2P,H) bf16, W2t(H,2P) bf16, D fp32
//   per slice (ws-adaptive): gemm1 MFMA -> Bu bf16; scan p1
//   scan p2  : global chunk carries
//   per slice: [gemm1 recompute if sliced], scan p3 in-place, gemm2 MFMA
//              -> out fp32 (+ u*D fused)

#define L_SEQ 16384
#define H_DIM 1024
#define P_DIM 1024
#define NCH   256
#define TCH   (L_SEQ / NCH)   // 64

typedef __bf16 bf16x8 __attribute__((ext_vector_type(8)));
typedef float  floatx4 __attribute__((ext_vector_type(4)));
using bf16 = __hip_bfloat16;

__device__ __forceinline__ void gld_lds16(const void* g, void* l) {
    __builtin_amdgcn_global_load_lds(
        (const __attribute__((address_space(1))) uint32_t*)g,
        (__attribute__((address_space(3))) uint32_t*)l, 16, 0, 0);
}

// read input element i as float, honoring detected dtype flag f
__device__ __forceinline__ float rd(const void* p, size_t i, int f) {
    return f ? ((const float*)p)[i]
             : __bfloat162float(((const bf16*)p)[i]);
}

// ---------------------------------------------------------------- detect
__global__ void detect_dtype(const uint16_t* __restrict__ u, int* __restrict__ flag) {
    __shared__ int cnt;
    if (threadIdx.x == 0) cnt = 0;
    __syncthreads();
    int c = 0;
    for (int i = threadIdx.x; i < 4096; i += 256) {
        int e = (u[i] >> 7) & 0xFF;
        if (e >= 134) c++;           // |x|>=128: never for bf16 N(0,1) data
    }
    atomicAdd(&cnt, c);
    __syncthreads();
    if (threadIdx.x == 0) *flag = (cnt > 64) ? 1 : 0;
}

// ---------------------------------------------------------------- convert u
__global__ void convert_u(const void* __restrict__ uin, const int* __restrict__ flag,
                          bf16* __restrict__ ub) {
    const int f = *flag;
    const size_t g = (size_t)blockIdx.x * 256 + threadIdx.x;  // group of 8
    if (f) {
        const float4* s = (const float4*)uin + g * 2;
        float4 a = s[0], b = s[1];
        alignas(16) bf16 t[8] = {
            __float2bfloat16(a.x), __float2bfloat16(a.y),
            __float2bfloat16(a.z), __float2bfloat16(a.w),
            __float2bfloat16(b.x), __float2bfloat16(b.y),
            __float2bfloat16(b.z), __float2bfloat16(b.w)};
        ((uint4*)ub)[g] = *(const uint4*)t;
    } else {
        ((uint4*)ub)[g] = ((const uint4*)uin)[g];
    }
}

// ---------------------------------------------------------------- prep
__global__ void prep_w1(const void* __restrict__ Lre, const void* __restrict__ Lim,
                        const void* __restrict__ lstep, const void* __restrict__ B,
                        const int* __restrict__ flag,
                        bf16* __restrict__ W1t, float2* __restrict__ lam,
                        float2* __restrict__ lamT) {
    const int f = *flag;
    const int p = blockIdx.x;
    float lr = fminf(rd(Lre, p, f), -1e-4f);
    float li = rd(Lim, p, f);
    float s  = expf(rd(lstep, p, f));
    float ea = expf(lr * s);
    float lbr = ea * cosf(li * s), lbi = ea * sinf(li * s);   // lambda_bar
    float dr = lbr - 1.0f, di = lbi;
    float den = lr * lr + li * li;
    float cr = (dr * lr + di * li) / den;                     // (lb-1)/Lambda
    float ci = (di * lr - dr * li) / den;
    if (threadIdx.x == 0) {
        lam[p] = make_float2(lbr, lbi);
        float tr = lbr, ti = lbi;                             // lambda_bar^64
        #pragma unroll
        for (int q = 0; q < 6; ++q) {
            float nr = tr * tr - ti * ti;
            float ni = 2.0f * tr * ti;
            tr = nr; ti = ni;
        }
        lamT[p] = make_float2(tr, ti);
    }
    for (int h = threadIdx.x; h < H_DIM; h += blockDim.x) {
        size_t base = ((size_t)p * H_DIM + h) * 2;
        float br = rd(B, base + 0, f);
        float bi = rd(B, base + 1, f);
        W1t[(size_t)p * H_DIM + h]           = __float2bfloat16(cr * br - ci * bi);
        W1t[(size_t)(P_DIM + p) * H_DIM + h] = __float2bfloat16(cr * bi + ci * br);
    }
}

__global__ void prep_w2(const void* __restrict__ C, const int* __restrict__ flag,
                        bf16* __restrict__ W2t) {
    const int f = *flag;
    const int h = blockIdx.x;
    for (int p = threadIdx.x; p < P_DIM; p += blockDim.x) {
        size_t base = ((size_t)h * P_DIM + p) * 2;
        W2t[(size_t)h * (2 * P_DIM) + p]         = __float2bfloat16( 2.0f * rd(C, base + 0, f));
        W2t[(size_t)h * (2 * P_DIM) + P_DIM + p] = __float2bfloat16(-2.0f * rd(C, base + 1, f));
    }
}

__global__ void prep_d(const void* __restrict__ D, const int* __restrict__ flag,
                       float* __restrict__ d_f) {
    const int h = blockIdx.x * 256 + threadIdx.x;
    d_f[h] = rd(D, h, *flag);
}

// ---------------------------------------------------------------- GEMM (m97 structure)
// A(M,K) bf16 rm, Bt(N,K) bf16 rm. EPI=false: OutBF bf16 = A@Bt^T.
// EPI=true: OutF fp32 = A@Bt^T + U*Dvec (U indexed at u_row0+row).
template <int N, int K, bool EPI>
__global__ __launch_bounds__(256) void gemm_bt(
    const bf16* __restrict__ A, const bf16* __restrict__ Bt,
    bf16* __restrict__ OutBF, float* __restrict__ OutF,
    const void* __restrict__ U, const int* __restrict__ Uflag, size_t u_row0,
    const float* __restrict__ Dvec) {
    __shared__ alignas(16) uint8_t sA[128 * 64];  // 128 rows x 32 bf16
    __shared__ alignas(16) uint8_t sB[128 * 64];

    const int tid  = threadIdx.x;
    const int wave = tid >> 6;
    const int lane = tid & 63;
    const int bm   = blockIdx.y * 128;
    const int bn   = blockIdx.x * 128;
    const int wm   = (wave >> 1) * 64;
    const int wn   = (wave & 1) * 64;

    floatx4 acc[4][4] = {};

    const int c0 = wave * 64 + lane;      // 16B chunk index
    const int r0 = c0 >> 2,  q0 = (c0 & 3) * 8;
    const int c1 = c0 + 256;
    const int r1 = c1 >> 2,  q1 = (c1 & 3) * 8;
    const int koff = (lane >> 4) * 16;    // byte offset of lane's k-slice
    const int fr   = lane & 15;

    for (int k0 = 0; k0 < K; k0 += 32) {
        gld_lds16(A  + (size_t)(bm + r0) * K + k0 + q0, sA + wave * 1024);
        gld_lds16(A  + (size_t)(bm + r1) * K + k0 + q1, sA + 4096 + wave * 1024);
        gld_lds16(Bt + (size_t)(bn + r0) * K + k0 + q0, sB + wave * 1024);
        gld_lds16(Bt + (size_t)(bn + r1) * K + k0 + q1, sB + 4096 + wave * 1024);
        __syncthreads();

        bf16x8 af[4], bfr[4];
        #pragma unroll
        for (int mi = 0; mi < 4; ++mi)
            af[mi] = *(const bf16x8*)(sA + (wm + mi * 16 + fr) * 64 + koff);
        #pragma unroll
        for (int ni = 0; ni < 4; ++ni)
            bfr[ni] = *(const bf16x8*)(sB + (wn + ni * 16 + fr) * 64 + koff);
        #pragma unroll
        for (int mi = 0; mi < 4; ++mi)
            #pragma unroll
            for (int ni = 0; ni < 4; ++ni)
                acc[mi][ni] = __builtin_amdgcn_mfma_f32_16x16x32_bf16(
                    af[mi], bfr[ni], acc[mi][ni], 0, 0, 0);
        __syncthreads();
    }

    const int uf = (EPI && Uflag) ? *Uflag : 0;
    const int col0  = bn + wn + fr;
    const int rbase = bm + wm + ((lane >> 4) << 2);
    #pragma unroll
    for (int mi = 0; mi < 4; ++mi) {
        #pragma unroll
        for (int r = 0; r < 4; ++r) {
            const int row = rbase + mi * 16 + r;
            #pragma unroll
            for (int ni = 0; ni < 4; ++ni) {
                const int c = col0 + ni * 16;
                float v = acc[mi][ni][r];
                if (EPI) {
                    float uu = rd(U, (u_row0 + row) * (size_t)H_DIM + c, uf);
                    OutF[(size_t)row * N + c] = v + uu * Dvec[c];
                } else {
                    OutBF[(size_t)row * N + c] = __float2bfloat16(v);
                }
            }
        }
    }
}

// ---------------------------------------------------------------- scan
__global__ void scan_phase1(const bf16* __restrict__ Bu,
                            const float2* __restrict__ lam,
                            float2* __restrict__ aggp) {
    const int p  = blockIdx.y * 256 + threadIdx.x;
    const int cl = blockIdx.x;
    const float2 lb = lam[p];
    float xr = 0.f, xi = 0.f;
    const bf16* b = Bu + (size_t)cl * TCH * (2 * P_DIM) + p;
    #pragma unroll 4
    for (int j = 0; j < TCH; ++j) {
        float bre = __bfloat162float(b[0]);
        float bim = __bfloat162float(b[P_DIM]);
        float nr = lb.x * xr - lb.y * xi + bre;
        float ni = lb.x * xi + lb.y * xr + bim;
        xr = nr; xi = ni;
        b += 2 * P_DIM;
    }
    aggp[(size_t)cl * P_DIM + p] = make_float2(xr, xi);
}

__global__ void scan_phase2(const float2* __restrict__ agg,
                            const float2* __restrict__ lamT,
                            float2* __restrict__ carry) {
    const int p = blockIdx.x * 256 + threadIdx.x;
    const float2 lT = lamT[p];
    float cr = 0.f, ci = 0.f;
    for (int c = 0; c < NCH; ++c) {
        carry[(size_t)c * P_DIM + p] = make_float2(cr, ci);
        float2 a = agg[(size_t)c * P_DIM + p];
        float nr = lT.x * cr - lT.y * ci + a.x;
        float ni = lT.x * ci + lT.y * cr + a.y;
        cr = nr; ci = ni;
    }
}

__global__ void scan_phase3(bf16* __restrict__ BuX,                 // in-place
                            const float2* __restrict__ lam,
                            const float2* __restrict__ carryp) {
    const int p  = blockIdx.y * 256 + threadIdx.x;
    const int cl = blockIdx.x;
    const float2 lb = lam[p];
    const float2 c0 = carryp[(size_t)cl * P_DIM + p];
    float xr = c0.x, xi = c0.y;
    bf16* b = BuX + (size_t)cl * TCH * (2 * P_DIM) + p;
    #pragma unroll 4
    for (int j = 0; j < TCH; ++j) {
        float bre = __bfloat162float(b[0]);
        float bim = __bfloat162float(b[P_DIM]);
        float nr = lb.x * xr - lb.y * xi + bre;
        float ni = lb.x * xi + lb.y * xr + bim;
        xr = nr; xi = ni;
        b[0]     = __float2bfloat16(xr);
        b[P_DIM] = __float2bfloat16(xi);
        b += 2 * P_DIM;
    }
}

// ---------------------------------------------------------------- launch
extern "C" void kernel_launch(void* const* d_in, const int* in_sizes, int n_in,
                              void* d_out, int out_size, void* d_ws, size_t ws_size,
                              hipStream_t stream) {
    float* out = (float*)d_out;  // (L,H) fp32

    char* w = (char*)d_ws;
    int*    flag  = (int*)w;     w += 256;
    float2* lam   = (float2*)w;  w += (size_t)P_DIM * 8;
    float2* lamT  = (float2*)w;  w += (size_t)P_DIM * 8;
    float*  d_f   = (float*)w;   w += (size_t)H_DIM * 4;
    float2* agg   = (float2*)w;  w += (size_t)NCH * P_DIM * 8;          // 2 MB
    float2* carry = (float2*)w;  w += (size_t)NCH * P_DIM * 8;          // 2 MB
    bf16*   W1t   = (bf16*)w;    w += (size_t)2 * P_DIM * H_DIM * 2;    // 4 MB
    bf16*   W2t   = (bf16*)w;    w += (size_t)H_DIM * 2 * P_DIM * 2;    // 4 MB
    bf16*   ub    = (bf16*)w;    w += (size_t)L_SEQ * H_DIM * 2;        // 33.5 MB
    bf16*   Xbuf  = (bf16*)w;    // 67.1/S MB
    const size_t fixedB = (size_t)(w - (char*)d_ws);

    int S = 16;
    for (int c = 1; c <= 16; c *= 2)
        if (fixedB + 67108864ull / (unsigned)c <= ws_size) { S = c; break; }
    const int MS = L_SEQ / S;   // rows per slice
    const int CS = MS / TCH;    // chunks per slice

    detect_dtype<<<1, 256, 0, stream>>>((const uint16_t*)d_in[0], flag);
    convert_u<<<(L_SEQ * H_DIM / 8) / 256, 256, 0, stream>>>(d_in[0], flag, ub);
    prep_w1<<<P_DIM, 256, 0, stream>>>(d_in[1], d_in[2], d_in[6], d_in[3], flag,
                                       W1t, lam, lamT);
    prep_w2<<<H_DIM, 256, 0, stream>>>(d_in[4], flag, W2t);
    prep_d<<<H_DIM / 256, 256, 0, stream>>>(d_in[5], flag, d_f);

    // pass A: per-slice Bu (MFMA) + chunk aggregates
    for (int s = 0; s < S; ++s) {
        gemm_bt<2 * P_DIM, H_DIM, false>
            <<<dim3((2 * P_DIM) / 128, MS / 128), 256, 0, stream>>>(
                ub + (size_t)s * MS * H_DIM, W1t, Xbuf, nullptr,
                nullptr, nullptr, 0, nullptr);
        scan_phase1<<<dim3(CS, P_DIM / 256), 256, 0, stream>>>(
            Xbuf, lam, agg + (size_t)s * CS * P_DIM);
    }
    // global carries
    scan_phase2<<<P_DIM / 256, 256, 0, stream>>>(agg, lamT, carry);
    // pass B: [recompute Bu if sliced], local scan w/ carry, output GEMM
    for (int s = 0; s < S; ++s) {
        if (S > 1)
            gemm_bt<2 * P_DIM, H_DIM, false>
                <<<dim3((2 * P_DIM) / 128, MS / 128), 256, 0, stream>>>(
                    ub + (size_t)s * MS * H_DIM, W1t, Xbuf, nullptr,
                    nullptr, nullptr, 0, nullptr);
        scan_phase3<<<dim3(CS, P_DIM / 256), 256, 0, stream>>>(
            Xbuf, lam, carry + (size_t)s * CS * P_DIM);
        gemm_bt<H_DIM, 2 * P_DIM, true>
            <<<dim3(H_DIM / 128, MS / 128), 256, 0, stream>>>(
                Xbuf, W2t, nullptr, out + (size_t)s * MS * H_DIM,
                d_in[0], flag, (size_t)s * MS, d_f);
    }
}

// Round 5
// 373.363 us; speedup vs baseline: 1.1223x; 1.1223x over previous
//
#include <hip/hip_runtime.h>
#include <hip/hip_bf16.h>
#include <stdint.h>

// S5 layer: L=16384, H=1024, P=1024. fp32 in/out (verified round 4, pass).
// Round-5 changes (GEMM K-loop stall attack):
//   - BK=64 (32 MFMA per barrier drain, 32 KB LDS)
//   - XOR bank swizzle (K-chunk slot ^= row&7 on the GLOBAL side of
//     global_load_lds; fragment ds_read_b128 goes 8-way -> 2-way conflicts)
//   - XCD swizzle: by == bid%8 per XCD, bx fast -> A-tile sharers co-located,
//     barrier drains hit L2 (~200cyc) not HBM (~900cyc)
//   - interleaved re/im layout (cols 2p,2p+1): 4B/lane scan loads
//   - GEMM2 epilogue reads ub bf16 (not fp32 u), nontemporal fp32 out store
//   - prep fused to 2 kernels w/ per-block dtype self-detect (7 dispatches)

#define L_SEQ 16384
#define H_DIM 1024
#define P_DIM 1024
#define NCH   256
#define TCH   64

typedef __bf16 bf16x8 __attribute__((ext_vector_type(8)));
typedef float  floatx4 __attribute__((ext_vector_type(4)));
using bf16 = __hip_bfloat16;

__device__ __forceinline__ void gld_lds16(const void* g, void* l) {
    __builtin_amdgcn_global_load_lds(
        (const __attribute__((address_space(1))) uint32_t*)g,
        (__attribute__((address_space(3))) uint32_t*)l, 16, 0, 0);
}

__device__ __forceinline__ float lo_bf(uint32_t v) { return __uint_as_float(v << 16); }
__device__ __forceinline__ float hi_bf(uint32_t v) { return __uint_as_float(v & 0xffff0000u); }
__device__ __forceinline__ uint32_t pack_bf(float r, float i) {
    bf16 rb = __float2bfloat16(r), ib = __float2bfloat16(i);
    return ((uint32_t)(*(uint16_t*)&ib) << 16) | (uint32_t)(*(uint16_t*)&rb);
}

// read input element i as float, honoring dtype flag f (1 = fp32)
__device__ __forceinline__ float rd(const void* p, size_t i, int f) {
    return f ? ((const float*)p)[i]
             : __bfloat162float(((const bf16*)p)[i]);
}

// per-block dtype self-detect from u[0:2048] halfwords: fp32 data read as
// bf16 triggers |x|>=128 (exp>=134) ~48% of low halfwords; bf16 N(0,1) never.
__device__ __forceinline__ int detect_f32(const uint16_t* u) {
    __shared__ int cnt;
    if (threadIdx.x == 0) cnt = 0;
    __syncthreads();
    int c = 0;
    #pragma unroll
    for (int i = 0; i < 8; ++i) {
        int e = (u[threadIdx.x * 8 + i] >> 7) & 0xFF;
        c += (e >= 134);
    }
    if (c) atomicAdd(&cnt, c);
    __syncthreads();
    return cnt > 32;
}

// ---------------------------------------------------------------- convert u
__global__ void convert_u(const void* __restrict__ uin, bf16* __restrict__ ub) {
    const int f = detect_f32((const uint16_t*)uin);
    const size_t g = (size_t)blockIdx.x * 256 + threadIdx.x;  // group of 8
    if (f) {
        const float4* s = (const float4*)uin + g * 2;
        float4 a = s[0], b = s[1];
        alignas(16) bf16 t[8] = {
            __float2bfloat16(a.x), __float2bfloat16(a.y),
            __float2bfloat16(a.z), __float2bfloat16(a.w),
            __float2bfloat16(b.x), __float2bfloat16(b.y),
            __float2bfloat16(b.z), __float2bfloat16(b.w)};
        ((uint4*)ub)[g] = *(const uint4*)t;
    } else {
        ((uint4*)ub)[g] = ((const uint4*)uin)[g];
    }
}

// ---------------------------------------------------------------- prep (fused)
// block b: state p=b -> lam, lam^64, W1t rows 2p/2p+1; head h=b -> W2t row;
// d_f[b]. Interleaved layout: col 2p = re, col 2p+1 = im.
__global__ void prep_all(const void* __restrict__ u,
                         const void* __restrict__ Lre, const void* __restrict__ Lim,
                         const void* __restrict__ lstep, const void* __restrict__ B,
                         const void* __restrict__ C, const void* __restrict__ D,
                         bf16* __restrict__ W1t, bf16* __restrict__ W2t,
                         float* __restrict__ d_f,
                         float2* __restrict__ lam, float2* __restrict__ lamT) {
    const int f = detect_f32((const uint16_t*)u);
    const int p = blockIdx.x;
    float lr = fminf(rd(Lre, p, f), -1e-4f);
    float li = rd(Lim, p, f);
    float s  = expf(rd(lstep, p, f));
    float ea = expf(lr * s);
    float lbr = ea * cosf(li * s), lbi = ea * sinf(li * s);   // lambda_bar
    float dr = lbr - 1.0f, di = lbi;
    float den = lr * lr + li * li;
    float cr = (dr * lr + di * li) / den;                     // (lb-1)/Lambda
    float ci = (di * lr - dr * li) / den;
    if (threadIdx.x == 0) {
        lam[p] = make_float2(lbr, lbi);
        float tr = lbr, ti = lbi;                             // lambda_bar^64
        #pragma unroll
        for (int q = 0; q < 6; ++q) {
            float nr = tr * tr - ti * ti, ni = 2.0f * tr * ti;
            tr = nr; ti = ni;
        }
        lamT[p] = make_float2(tr, ti);
        d_f[p] = rd(D, p, f);
    }
    for (int h = threadIdx.x; h < H_DIM; h += blockDim.x) {
        size_t base = ((size_t)p * H_DIM + h) * 2;
        float br = rd(B, base + 0, f);
        float bi = rd(B, base + 1, f);
        W1t[(size_t)(2 * p)     * H_DIM + h] = __float2bfloat16(cr * br - ci * bi);
        W1t[(size_t)(2 * p + 1) * H_DIM + h] = __float2bfloat16(cr * bi + ci * br);
    }
    const int h = blockIdx.x;   // reuse block as head index (H == P)
    for (int q = threadIdx.x; q < P_DIM; q += blockDim.x) {
        size_t base = ((size_t)h * P_DIM + q) * 2;
        W2t[(size_t)h * (2 * P_DIM) + 2 * q]     = __float2bfloat16( 2.0f * rd(C, base + 0, f));
        W2t[(size_t)h * (2 * P_DIM) + 2 * q + 1] = __float2bfloat16(-2.0f * rd(C, base + 1, f));
    }
}

// ---------------------------------------------------------------- GEMM
// A(M,K) bf16 rm, Bt(N,K) bf16 rm. 128x128 tile, BK=64, XOR bank swizzle,
// XCD swizzle. EPI=false: OutBF bf16. EPI=true: OutF fp32 = acc + U*Dvec (nt).
template <int N, int K, bool EPI>
__global__ __launch_bounds__(256) void gemm_bt(
    const bf16* __restrict__ A, const bf16* __restrict__ Bt,
    bf16* __restrict__ OutBF, float* __restrict__ OutF,
    const bf16* __restrict__ U, const float* __restrict__ Dvec) {
    constexpr int NXB = N / 128;
    __shared__ alignas(16) uint8_t sA[128 * 128];   // 128 rows x 64 bf16
    __shared__ alignas(16) uint8_t sB[128 * 128];

    const int tid  = threadIdx.x;
    const int wave = tid >> 6;
    const int lane = tid & 63;
    // XCD swizzle: by == bid (mod 8) -> constant per XCD; bx fast within.
    const int bid = blockIdx.x;
    const int xr  = bid & 7;
    const int jj  = bid >> 3;
    const int bx  = jj % NXB;
    const int by  = (jj / NXB) * 8 + xr;
    const int bm  = by * 128, bn = bx * 128;
    const int wm  = (wave >> 1) * 64, wn = (wave & 1) * 64;

    floatx4 acc[4][4] = {};

    const int fr   = lane & 15;
    const int kq   = lane >> 4;        // 0..3
    const int srow = tid >> 3;         // staging row within 32-row group
    const int skc  = tid & 7;          // staging 16B-chunk slot

    for (int k0 = 0; k0 < K; k0 += 64) {
        #pragma unroll
        for (int q = 0; q < 4; ++q) {
            const int row = q * 32 + srow;
            const int kcg = skc ^ (row & 7);   // XOR swizzle on global side
            gld_lds16(A  + (size_t)(bm + row) * K + k0 + kcg * 8,
                      sA + q * 4096 + wave * 1024);
            gld_lds16(Bt + (size_t)(bn + row) * K + k0 + kcg * 8,
                      sB + q * 4096 + wave * 1024);
        }
        __syncthreads();
        #pragma unroll
        for (int s = 0; s < 2; ++s) {
            bf16x8 af[4], bfr[4];
            #pragma unroll
            for (int mi = 0; mi < 4; ++mi) {
                const int row = wm + mi * 16 + fr;
                const int ch  = (s * 4 + kq) ^ (row & 7);
                af[mi] = *(const bf16x8*)(sA + row * 128 + ch * 16);
            }
            #pragma unroll
            for (int ni = 0; ni < 4; ++ni) {
                const int row = wn + ni * 16 + fr;
                const int ch  = (s * 4 + kq) ^ (row & 7);
                bfr[ni] = *(const bf16x8*)(sB + row * 128 + ch * 16);
            }
            #pragma unroll
            for (int mi = 0; mi < 4; ++mi)
                #pragma unroll
                for (int ni = 0; ni < 4; ++ni)
                    acc[mi][ni] = __builtin_amdgcn_mfma_f32_16x16x32_bf16(
                        af[mi], bfr[ni], acc[mi][ni], 0, 0, 0);
        }
        __syncthreads();
    }

    const int col0  = bn + wn + fr;
    const int rbase = bm + wm + kq * 4;
    #pragma unroll
    for (int mi = 0; mi < 4; ++mi) {
        #pragma unroll
        for (int rr = 0; rr < 4; ++rr) {
            const int row = rbase + mi * 16 + rr;
            #pragma unroll
            for (int ni = 0; ni < 4; ++ni) {
                const int c = col0 + ni * 16;
                float v = acc[mi][ni][rr];
                if (EPI) {
                    float uu = __bfloat162float(U[(size_t)row * H_DIM + c]);
                    __builtin_nontemporal_store(v + uu * Dvec[c],
                                                &OutF[(size_t)row * N + c]);
                } else {
                    OutBF[(size_t)row * N + c] = __float2bfloat16(v);
                }
            }
        }
    }
}

// ---------------------------------------------------------------- scan
// Interleaved layout: row = P_DIM uint32 words; word p = (re_p | im_p<<16).
__global__ void scan_phase1(const uint32_t* __restrict__ Bu,
                            const float2* __restrict__ lam,
                            float2* __restrict__ agg) {
    const int p = blockIdx.y * 256 + threadIdx.x;
    const int c = blockIdx.x;
    const float2 lb = lam[p];
    float xr = 0.f, xi = 0.f;
    const uint32_t* b = Bu + (size_t)c * TCH * P_DIM + p;
    #pragma unroll 4
    for (int j = 0; j < TCH; ++j) {
        uint32_t v = *b;
        float nr = lb.x * xr - lb.y * xi + lo_bf(v);
        float ni = lb.x * xi + lb.y * xr + hi_bf(v);
        xr = nr; xi = ni;
        b += P_DIM;
    }
    agg[(size_t)c * P_DIM + p] = make_float2(xr, xi);
}

__global__ void scan_phase2(const float2* __restrict__ agg,
                            const float2* __restrict__ lamT,
                            float2* __restrict__ carry) {
    const int p = blockIdx.x * 256 + threadIdx.x;
    const float2 lT = lamT[p];
    float cr = 0.f, ci = 0.f;
    #pragma unroll 4
    for (int c = 0; c < NCH; ++c) {
        carry[(size_t)c * P_DIM + p] = make_float2(cr, ci);
        float2 a = agg[(size_t)c * P_DIM + p];
        float nr = lT.x * cr - lT.y * ci + a.x;
        float ni = lT.x * ci + lT.y * cr + a.y;
        cr = nr; ci = ni;
    }
}

__global__ void scan_phase3(uint32_t* __restrict__ BuX,             // in-place
                            const float2* __restrict__ lam,
                            const float2* __restrict__ carry) {
    const int p = blockIdx.y * 256 + threadIdx.x;
    const int c = blockIdx.x;
    const float2 lb = lam[p];
    const float2 c0 = carry[(size_t)c * P_DIM + p];
    float xr = c0.x, xi = c0.y;
    uint32_t* b = BuX + (size_t)c * TCH * P_DIM + p;
    #pragma unroll 4
    for (int j = 0; j < TCH; ++j) {
        uint32_t v = *b;
        float nr = lb.x * xr - lb.y * xi + lo_bf(v);
        float ni = lb.x * xi + lb.y * xr + hi_bf(v);
        xr = nr; xi = ni;
        *b = pack_bf(xr, xi);
        b += P_DIM;
    }
}

// ---------------------------------------------------------------- launch
extern "C" void kernel_launch(void* const* d_in, const int* in_sizes, int n_in,
                              void* d_out, int out_size, void* d_ws, size_t ws_size,
                              hipStream_t stream) {
    float* out = (float*)d_out;  // (L,H) fp32

    char* w = (char*)d_ws;
    w += 256;                                                        // (pad)
    float2* lam   = (float2*)w;  w += (size_t)P_DIM * 8;
    float2* lamT  = (float2*)w;  w += (size_t)P_DIM * 8;
    float*  d_f   = (float*)w;   w += (size_t)H_DIM * 4;
    float2* agg   = (float2*)w;  w += (size_t)NCH * P_DIM * 8;       // 2 MB
    float2* carry = (float2*)w;  w += (size_t)NCH * P_DIM * 8;       // 2 MB
    bf16*   W1t   = (bf16*)w;    w += (size_t)2 * P_DIM * H_DIM * 2; // 4 MB
    bf16*   W2t   = (bf16*)w;    w += (size_t)H_DIM * 2 * P_DIM * 2; // 4 MB
    bf16*   ub    = (bf16*)w;    w += (size_t)L_SEQ * H_DIM * 2;     // 33.5 MB
    bf16*   Xbuf  = (bf16*)w;                                        // 67 MB

    convert_u<<<(L_SEQ * H_DIM / 8) / 256, 256, 0, stream>>>(d_in[0], ub);
    prep_all<<<P_DIM, 256, 0, stream>>>(d_in[0], d_in[1], d_in[2], d_in[6],
                                        d_in[3], d_in[4], d_in[5],
                                        W1t, W2t, d_f, lam, lamT);

    // Bu(L,2P) = ub @ W1t^T   (interleaved cols)
    gemm_bt<2 * P_DIM, H_DIM, false><<<(2 * P_DIM / 128) * 128, 256, 0, stream>>>(
        ub, W1t, Xbuf, nullptr, nullptr, nullptr);

    scan_phase1<<<dim3(NCH, P_DIM / 256), 256, 0, stream>>>(
        (const uint32_t*)Xbuf, lam, agg);
    scan_phase2<<<P_DIM / 256, 256, 0, stream>>>(agg, lamT, carry);
    scan_phase3<<<dim3(NCH, P_DIM / 256), 256, 0, stream>>>(
        (uint32_t*)Xbuf, lam, carry);

    // out = X @ W2t^T + ub*D
    gemm_bt<H_DIM, 2 * P_DIM, true><<<(H_DIM / 128) * 128, 256, 0, stream>>>(
        Xbuf, W2t, nullptr, out, ub, d_f);
}

// Round 6
// 361.858 us; speedup vs baseline: 1.1580x; 1.0318x over previous
//
#include <hip/hip_runtime.h>
#include <hip/hip_bf16.h>
#include <stdint.h>

// S5 layer: L=16384, H=1024, P=1024. fp32 in/out. Round-6:
//   - phase1 FUSED into GEMM1 epilogue: agg_c(p) = sum_t lam^(63-t)*Bu_t(p)
//     computed from the acc registers via LDS lambda-power table (reuses the
//     32KB staging LDS after the K-loop) + paired-lane re/im exchange +
//     kq butterfly reduce. Eliminates the 67MB phase1 re-read.
//   - phase2 wave-parallel: 1 wave/state; lane j owns 4 chunks (local
//     exclusive scan, lam^64), Hillis-Steele affine-pair scan across lanes
//     (lam^256), re-apply. Was a 16-wave, 256-serial-step kernel.
//   - GEMM K-loops byte-identical to round 5 (at m97-structure plateau:
//     MfmaUtil 29.5%, 0 bank conflicts, FETCH 82MB).

#define L_SEQ 16384
#define H_DIM 1024
#define P_DIM 1024
#define NCH   256
#define TCH   64

typedef __bf16 bf16x8 __attribute__((ext_vector_type(8)));
typedef float  floatx4 __attribute__((ext_vector_type(4)));
using bf16 = __hip_bfloat16;

__device__ __forceinline__ void gld_lds16(const void* g, void* l) {
    __builtin_amdgcn_global_load_lds(
        (const __attribute__((address_space(1))) uint32_t*)g,
        (__attribute__((address_space(3))) uint32_t*)l, 16, 0, 0);
}

__device__ __forceinline__ float lo_bf(uint32_t v) { return __uint_as_float(v << 16); }
__device__ __forceinline__ float hi_bf(uint32_t v) { return __uint_as_float(v & 0xffff0000u); }
__device__ __forceinline__ uint32_t pack_bf(float r, float i) {
    bf16 rb = __float2bfloat16(r), ib = __float2bfloat16(i);
    return ((uint32_t)(*(uint16_t*)&ib) << 16) | (uint32_t)(*(uint16_t*)&rb);
}

__device__ __forceinline__ float rd(const void* p, size_t i, int f) {
    return f ? ((const float*)p)[i]
             : __bfloat162float(((const bf16*)p)[i]);
}

// per-block dtype self-detect (fp32 halfwords read as bf16 show |x|>=128)
__device__ __forceinline__ int detect_f32(const uint16_t* u) {
    __shared__ int cnt;
    if (threadIdx.x == 0) cnt = 0;
    __syncthreads();
    int c = 0;
    #pragma unroll
    for (int i = 0; i < 8; ++i) {
        int e = (u[threadIdx.x * 8 + i] >> 7) & 0xFF;
        c += (e >= 134);
    }
    if (c) atomicAdd(&cnt, c);
    __syncthreads();
    return cnt > 32;
}

// ---------------------------------------------------------------- convert u
__global__ void convert_u(const void* __restrict__ uin, bf16* __restrict__ ub) {
    const int f = detect_f32((const uint16_t*)uin);
    const size_t g = (size_t)blockIdx.x * 256 + threadIdx.x;
    if (f) {
        const float4* s = (const float4*)uin + g * 2;
        float4 a = s[0], b = s[1];
        alignas(16) bf16 t[8] = {
            __float2bfloat16(a.x), __float2bfloat16(a.y),
            __float2bfloat16(a.z), __float2bfloat16(a.w),
            __float2bfloat16(b.x), __float2bfloat16(b.y),
            __float2bfloat16(b.z), __float2bfloat16(b.w)};
        ((uint4*)ub)[g] = *(const uint4*)t;
    } else {
        ((uint4*)ub)[g] = ((const uint4*)uin)[g];
    }
}

// ---------------------------------------------------------------- prep (fused)
__global__ void prep_all(const void* __restrict__ u,
                         const void* __restrict__ Lre, const void* __restrict__ Lim,
                         const void* __restrict__ lstep, const void* __restrict__ B,
                         const void* __restrict__ C, const void* __restrict__ D,
                         bf16* __restrict__ W1t, bf16* __restrict__ W2t,
                         float* __restrict__ d_f,
                         float2* __restrict__ lam, float2* __restrict__ lamT) {
    const int f = detect_f32((const uint16_t*)u);
    const int p = blockIdx.x;
    float lr = fminf(rd(Lre, p, f), -1e-4f);
    float li = rd(Lim, p, f);
    float s  = expf(rd(lstep, p, f));
    float ea = expf(lr * s);
    float lbr = ea * cosf(li * s), lbi = ea * sinf(li * s);   // lambda_bar
    float dr = lbr - 1.0f, di = lbi;
    float den = lr * lr + li * li;
    float cr = (dr * lr + di * li) / den;                     // (lb-1)/Lambda
    float ci = (di * lr - dr * li) / den;
    if (threadIdx.x == 0) {
        lam[p] = make_float2(lbr, lbi);
        float tr = lbr, ti = lbi;                             // lambda_bar^64
        #pragma unroll
        for (int q = 0; q < 6; ++q) {
            float nr = tr * tr - ti * ti, ni = 2.0f * tr * ti;
            tr = nr; ti = ni;
        }
        lamT[p] = make_float2(tr, ti);
        d_f[p] = rd(D, p, f);
    }
    for (int h = threadIdx.x; h < H_DIM; h += blockDim.x) {
        size_t base = ((size_t)p * H_DIM + h) * 2;
        float br = rd(B, base + 0, f);
        float bi = rd(B, base + 1, f);
        W1t[(size_t)(2 * p)     * H_DIM + h] = __float2bfloat16(cr * br - ci * bi);
        W1t[(size_t)(2 * p + 1) * H_DIM + h] = __float2bfloat16(cr * bi + ci * br);
    }
    const int h = blockIdx.x;
    for (int q = threadIdx.x; q < P_DIM; q += blockDim.x) {
        size_t base = ((size_t)h * P_DIM + q) * 2;
        W2t[(size_t)h * (2 * P_DIM) + 2 * q]     = __float2bfloat16( 2.0f * rd(C, base + 0, f));
        W2t[(size_t)h * (2 * P_DIM) + 2 * q + 1] = __float2bfloat16(-2.0f * rd(C, base + 1, f));
    }
}

// ---------------------------------------------------------------- GEMM
// A(M,K) bf16 rm, Bt(N,K) bf16 rm. 128x128 tile, BK=64, XOR bank swizzle,
// XCD swizzle. MODE 1: OutBF bf16 + fused chunk-aggregates (phase1).
// MODE 2: OutF fp32 = acc + U*Dvec, nontemporal.
template <int N, int K, int MODE>
__global__ __launch_bounds__(256) void gemm_bt(
    const bf16* __restrict__ A, const bf16* __restrict__ Bt,
    bf16* __restrict__ OutBF, float* __restrict__ OutF,
    const bf16* __restrict__ U, const float* __restrict__ Dvec,
    const float2* __restrict__ lam, float2* __restrict__ aggp) {
    constexpr int NXB = N / 128;
    __shared__ alignas(16) uint8_t smem[32768];
    uint8_t* sA = smem;
    uint8_t* sB = smem + 16384;

    const int tid  = threadIdx.x;
    const int wave = tid >> 6;
    const int lane = tid & 63;
    const int bid = blockIdx.x;
    const int xr  = bid & 7;
    const int jj  = bid >> 3;
    const int bx  = jj % NXB;
    const int by  = (jj / NXB) * 8 + xr;
    const int bm  = by * 128, bn = bx * 128;
    const int wm  = (wave >> 1) * 64, wn = (wave & 1) * 64;

    floatx4 acc[4][4] = {};

    const int fr   = lane & 15;
    const int kq   = lane >> 4;        // 0..3
    const int srow = tid >> 3;
    const int skc  = tid & 7;

    for (int k0 = 0; k0 < K; k0 += 64) {
        #pragma unroll
        for (int q = 0; q < 4; ++q) {
            const int row = q * 32 + srow;
            const int kcg = skc ^ (row & 7);
            gld_lds16(A  + (size_t)(bm + row) * K + k0 + kcg * 8,
                      sA + q * 4096 + wave * 1024);
            gld_lds16(Bt + (size_t)(bn + row) * K + k0 + kcg * 8,
                      sB + q * 4096 + wave * 1024);
        }
        __syncthreads();
        #pragma unroll
        for (int s = 0; s < 2; ++s) {
            bf16x8 af[4], bfr[4];
            #pragma unroll
            for (int mi = 0; mi < 4; ++mi) {
                const int row = wm + mi * 16 + fr;
                const int ch  = (s * 4 + kq) ^ (row & 7);
                af[mi] = *(const bf16x8*)(sA + row * 128 + ch * 16);
            }
            #pragma unroll
            for (int ni = 0; ni < 4; ++ni) {
                const int row = wn + ni * 16 + fr;
                const int ch  = (s * 4 + kq) ^ (row & 7);
                bfr[ni] = *(const bf16x8*)(sB + row * 128 + ch * 16);
            }
            #pragma unroll
            for (int mi = 0; mi < 4; ++mi)
                #pragma unroll
                for (int ni = 0; ni < 4; ++ni)
                    acc[mi][ni] = __builtin_amdgcn_mfma_f32_16x16x32_bf16(
                        af[mi], bfr[ni], acc[mi][ni], 0, 0, 0);
        }
        __syncthreads();
    }

    const int col0  = bn + wn + fr;
    const int rbase = bm + wm + kq * 4;
    #pragma unroll
    for (int mi = 0; mi < 4; ++mi) {
        #pragma unroll
        for (int rr = 0; rr < 4; ++rr) {
            const int row = rbase + mi * 16 + rr;
            #pragma unroll
            for (int ni = 0; ni < 4; ++ni) {
                const int c = col0 + ni * 16;
                float v = acc[mi][ni][rr];
                if (MODE == 2) {
                    float uu = __bfloat162float(U[(size_t)row * H_DIM + c]);
                    __builtin_nontemporal_store(v + uu * Dvec[c],
                                                &OutF[(size_t)row * N + c]);
                } else {
                    OutBF[(size_t)row * N + c] = __float2bfloat16(v);
                }
            }
        }
    }

    if (MODE == 1) {
        // ---- fused phase1: chunk aggregates from acc registers ----
        // wtab[q_local][t] = lam_q^(63-t), q_local in [0,64), t in [0,64)
        float2* wtab = (float2*)smem;    // 32KB, reuses staging LDS
        {
            const int ql = tid >> 2;            // 0..63
            const int t0 = (tid & 3) * 16;      // 0,16,32,48
            float2 lb = lam[(bn >> 1) + ql];
            float tr = lb.x, ti = lb.y;         // -> lb^16
            #pragma unroll
            for (int q = 0; q < 4; ++q) {
                float nr = tr * tr - ti * ti, ni = 2.f * tr * ti;
                tr = nr; ti = ni;
            }
            float p32r = tr * tr - ti * ti, p32i = 2.f * tr * ti;
            float wr, wi;                       // lb^(48-t0)
            if (t0 == 0)       { wr = p32r * tr - p32i * ti; wi = p32r * ti + p32i * tr; }
            else if (t0 == 16) { wr = p32r; wi = p32i; }
            else if (t0 == 32) { wr = tr;   wi = ti; }
            else               { wr = 1.f;  wi = 0.f; }
            #pragma unroll
            for (int j = 15; j >= 0; --j) {     // t descending => power ascending
                wtab[ql * 64 + t0 + j] = make_float2(wr, wi);
                float nr = wr * lb.x - wi * lb.y;
                float ni = wr * lb.y + wi * lb.x;
                wr = nr; wi = ni;
            }
        }
        __syncthreads();
        const int par = fr & 1;                 // 0: re lane, 1: im lane
        const int cg  = (bm + wm) >> 6;         // global chunk of this wave
        #pragma unroll
        for (int ni = 0; ni < 4; ++ni) {
            const int ql = (wn + ni * 16 + (fr & ~1)) >> 1;   // 0..63
            float s = 0.f;
            #pragma unroll
            for (int mi = 0; mi < 4; ++mi)
                #pragma unroll
                for (int rr = 0; rr < 4; ++rr) {
                    const int t = mi * 16 + kq * 4 + rr;
                    float own  = acc[mi][ni][rr];
                    float part = __shfl_xor(own, 1);
                    float2 wv = wtab[ql * 64 + t];
                    s += wv.x * own + (par ? wv.y : -wv.y) * part;
                }
            s += __shfl_xor(s, 16);             // reduce over kq
            s += __shfl_xor(s, 32);
            float other = __shfl_xor(s, 1);     // partner component
            if (kq == 0 && par == 0)
                aggp[(size_t)cg * P_DIM + (bn >> 1) + ql] = make_float2(s, other);
        }
    }
}

// ---------------------------------------------------------------- scan
// phase2: wave-parallel carries. 1 wave per state; lane j owns chunks 4j..4j+3.
__global__ void scan_phase2p(const float2* __restrict__ agg,
                             const float2* __restrict__ lamT,
                             float2* __restrict__ carry) {
    const int w = threadIdx.x >> 6;
    const int j = threadIdx.x & 63;
    const int p = blockIdx.x * 4 + w;
    const float2 A = lamT[p];                               // lam^64
    float b2r = A.x * A.x - A.y * A.y, b2i = 2.f * A.x * A.y;
    float Br = b2r * b2r - b2i * b2i, Bi = 2.f * b2r * b2i; // lam^256
    float2 a[4];
    #pragma unroll
    for (int k = 0; k < 4; ++k) a[k] = agg[(size_t)(4 * j + k) * P_DIM + p];
    // lane total (zero-seeded inclusive over 4 chunks)
    float xr = 0.f, xi = 0.f;
    #pragma unroll
    for (int k = 0; k < 4; ++k) {
        float nr = A.x * xr - A.y * xi + a[k].x;
        float ni = A.x * xi + A.y * xr + a[k].y;
        xr = nr; xi = ni;
    }
    // Hillis-Steele affine-pair scan across lanes: map x -> c*x + v
    float cr = Br, ci = Bi, vr = xr, vi = xi;
    #pragma unroll
    for (int d = 1; d < 64; d <<= 1) {
        float pvr = __shfl_up(vr, d), pvi = __shfl_up(vi, d);
        float pcr = __shfl_up(cr, d), pci = __shfl_up(ci, d);
        if (j >= d) {
            float nvr = cr * pvr - ci * pvi + vr;
            float nvi = cr * pvi + ci * pvr + vi;
            float ncr = cr * pcr - ci * pci;
            float nci = cr * pci + ci * pcr;
            vr = nvr; vi = nvi; cr = ncr; ci = nci;
        }
    }
    float sr = __shfl_up(vr, 1), si = __shfl_up(vi, 1);     // exclusive seed
    if (j == 0) { sr = 0.f; si = 0.f; }
    #pragma unroll
    for (int k = 0; k < 4; ++k) {
        carry[(size_t)(4 * j + k) * P_DIM + p] = make_float2(sr, si);
        float nr = A.x * sr - A.y * si + a[k].x;
        float ni = A.x * si + A.y * sr + a[k].y;
        sr = nr; si = ni;
    }
}

__global__ void scan_phase3(uint32_t* __restrict__ BuX,             // in-place
                            const float2* __restrict__ lam,
                            const float2* __restrict__ carry) {
    const int p = blockIdx.y * 256 + threadIdx.x;
    const int c = blockIdx.x;
    const float2 lb = lam[p];
    const float2 c0 = carry[(size_t)c * P_DIM + p];
    float xr = c0.x, xi = c0.y;
    uint32_t* b = BuX + (size_t)c * TCH * P_DIM + p;
    #pragma unroll 4
    for (int j = 0; j < TCH; ++j) {
        uint32_t v = *b;
        float nr = lb.x * xr - lb.y * xi + lo_bf(v);
        float ni = lb.x * xi + lb.y * xr + hi_bf(v);
        xr = nr; xi = ni;
        *b = pack_bf(xr, xi);
        b += P_DIM;
    }
}

// ---------------------------------------------------------------- launch
extern "C" void kernel_launch(void* const* d_in, const int* in_sizes, int n_in,
                              void* d_out, int out_size, void* d_ws, size_t ws_size,
                              hipStream_t stream) {
    float* out = (float*)d_out;  // (L,H) fp32

    char* w = (char*)d_ws;
    w += 256;
    float2* lam   = (float2*)w;  w += (size_t)P_DIM * 8;
    float2* lamT  = (float2*)w;  w += (size_t)P_DIM * 8;
    float*  d_f   = (float*)w;   w += (size_t)H_DIM * 4;
    float2* agg   = (float2*)w;  w += (size_t)NCH * P_DIM * 8;       // 2 MB
    float2* carry = (float2*)w;  w += (size_t)NCH * P_DIM * 8;       // 2 MB
    bf16*   W1t   = (bf16*)w;    w += (size_t)2 * P_DIM * H_DIM * 2; // 4 MB
    bf16*   W2t   = (bf16*)w;    w += (size_t)H_DIM * 2 * P_DIM * 2; // 4 MB
    bf16*   ub    = (bf16*)w;    w += (size_t)L_SEQ * H_DIM * 2;     // 33.5 MB
    bf16*   Xbuf  = (bf16*)w;                                        // 67 MB

    convert_u<<<(L_SEQ * H_DIM / 8) / 256, 256, 0, stream>>>(d_in[0], ub);
    prep_all<<<P_DIM, 256, 0, stream>>>(d_in[0], d_in[1], d_in[2], d_in[6],
                                        d_in[3], d_in[4], d_in[5],
                                        W1t, W2t, d_f, lam, lamT);

    // Bu(L,2P) = ub @ W1t^T  (interleaved cols) + fused chunk aggregates
    gemm_bt<2 * P_DIM, H_DIM, 1><<<(2 * P_DIM / 128) * 128, 256, 0, stream>>>(
        ub, W1t, Xbuf, nullptr, nullptr, nullptr, lam, agg);

    scan_phase2p<<<P_DIM / 4, 256, 0, stream>>>(agg, lamT, carry);
    scan_phase3<<<dim3(NCH, P_DIM / 256), 256, 0, stream>>>(
        (uint32_t*)Xbuf, lam, carry);

    // out = X @ W2t^T + ub*D
    gemm_bt<H_DIM, 2 * P_DIM, 2><<<(H_DIM / 128) * 128, 256, 0, stream>>>(
        Xbuf, W2t, nullptr, out, ub, d_f, nullptr, nullptr);
}

// Round 7
// 352.874 us; speedup vs baseline: 1.1875x; 1.0255x over previous
//
#include <hip/hip_runtime.h>
#include <hip/hip_bf16.h>
#include <stdint.h>

// S5 layer: L=16384, H=1024, P=1024. fp32 in/out. Round-7:
//   - REVERT GEMM LDS to two separate __shared__ arrays (round-6's generic
//     pointer smem broke addrspace inference: 6.8e6 bank conflicts, both
//     GEMMs 95->112us; round-5 form had 0 conflicts).
//   - fused phase1 aggregate epilogue rebuilt REGISTER-ONLY: per-lane weight
//     lam^(63-t) via iterative complex multiply (init lam^(12-4kq), step
//     x lam per t, x lam^12 per mi-group). No wtab LDS, no extra barrier.
//   - rest unchanged: phase2 wave-parallel carries, phase3 in-place scan,
//     convert u->bf16, fused prep.

#define L_SEQ 16384
#define H_DIM 1024
#define P_DIM 1024
#define NCH   256
#define TCH   64

typedef __bf16 bf16x8 __attribute__((ext_vector_type(8)));
typedef float  floatx4 __attribute__((ext_vector_type(4)));
using bf16 = __hip_bfloat16;

__device__ __forceinline__ void gld_lds16(const void* g, void* l) {
    __builtin_amdgcn_global_load_lds(
        (const __attribute__((address_space(1))) uint32_t*)g,
        (__attribute__((address_space(3))) uint32_t*)l, 16, 0, 0);
}

__device__ __forceinline__ float lo_bf(uint32_t v) { return __uint_as_float(v << 16); }
__device__ __forceinline__ float hi_bf(uint32_t v) { return __uint_as_float(v & 0xffff0000u); }
__device__ __forceinline__ uint32_t pack_bf(float r, float i) {
    bf16 rb = __float2bfloat16(r), ib = __float2bfloat16(i);
    return ((uint32_t)(*(uint16_t*)&ib) << 16) | (uint32_t)(*(uint16_t*)&rb);
}

__device__ __forceinline__ float rd(const void* p, size_t i, int f) {
    return f ? ((const float*)p)[i]
             : __bfloat162float(((const bf16*)p)[i]);
}

// per-block dtype self-detect (fp32 halfwords read as bf16 show |x|>=128)
__device__ __forceinline__ int detect_f32(const uint16_t* u) {
    __shared__ int cnt;
    if (threadIdx.x == 0) cnt = 0;
    __syncthreads();
    int c = 0;
    #pragma unroll
    for (int i = 0; i < 8; ++i) {
        int e = (u[threadIdx.x * 8 + i] >> 7) & 0xFF;
        c += (e >= 134);
    }
    if (c) atomicAdd(&cnt, c);
    __syncthreads();
    return cnt > 32;
}

// ---------------------------------------------------------------- convert u
__global__ void convert_u(const void* __restrict__ uin, bf16* __restrict__ ub) {
    const int f = detect_f32((const uint16_t*)uin);
    const size_t g = (size_t)blockIdx.x * 256 + threadIdx.x;
    if (f) {
        const float4* s = (const float4*)uin + g * 2;
        float4 a = s[0], b = s[1];
        alignas(16) bf16 t[8] = {
            __float2bfloat16(a.x), __float2bfloat16(a.y),
            __float2bfloat16(a.z), __float2bfloat16(a.w),
            __float2bfloat16(b.x), __float2bfloat16(b.y),
            __float2bfloat16(b.z), __float2bfloat16(b.w)};
        ((uint4*)ub)[g] = *(const uint4*)t;
    } else {
        ((uint4*)ub)[g] = ((const uint4*)uin)[g];
    }
}

// ---------------------------------------------------------------- prep (fused)
__global__ void prep_all(const void* __restrict__ u,
                         const void* __restrict__ Lre, const void* __restrict__ Lim,
                         const void* __restrict__ lstep, const void* __restrict__ B,
                         const void* __restrict__ C, const void* __restrict__ D,
                         bf16* __restrict__ W1t, bf16* __restrict__ W2t,
                         float* __restrict__ d_f,
                         float2* __restrict__ lam, float2* __restrict__ lamT) {
    const int f = detect_f32((const uint16_t*)u);
    const int p = blockIdx.x;
    float lr = fminf(rd(Lre, p, f), -1e-4f);
    float li = rd(Lim, p, f);
    float s  = expf(rd(lstep, p, f));
    float ea = expf(lr * s);
    float lbr = ea * cosf(li * s), lbi = ea * sinf(li * s);   // lambda_bar
    float dr = lbr - 1.0f, di = lbi;
    float den = lr * lr + li * li;
    float cr = (dr * lr + di * li) / den;                     // (lb-1)/Lambda
    float ci = (di * lr - dr * li) / den;
    if (threadIdx.x == 0) {
        lam[p] = make_float2(lbr, lbi);
        float tr = lbr, ti = lbi;                             // lambda_bar^64
        #pragma unroll
        for (int q = 0; q < 6; ++q) {
            float nr = tr * tr - ti * ti, ni = 2.0f * tr * ti;
            tr = nr; ti = ni;
        }
        lamT[p] = make_float2(tr, ti);
        d_f[p] = rd(D, p, f);
    }
    for (int h = threadIdx.x; h < H_DIM; h += blockDim.x) {
        size_t base = ((size_t)p * H_DIM + h) * 2;
        float br = rd(B, base + 0, f);
        float bi = rd(B, base + 1, f);
        W1t[(size_t)(2 * p)     * H_DIM + h] = __float2bfloat16(cr * br - ci * bi);
        W1t[(size_t)(2 * p + 1) * H_DIM + h] = __float2bfloat16(cr * bi + ci * br);
    }
    const int h = blockIdx.x;
    for (int q = threadIdx.x; q < P_DIM; q += blockDim.x) {
        size_t base = ((size_t)h * P_DIM + q) * 2;
        W2t[(size_t)h * (2 * P_DIM) + 2 * q]     = __float2bfloat16( 2.0f * rd(C, base + 0, f));
        W2t[(size_t)h * (2 * P_DIM) + 2 * q + 1] = __float2bfloat16(-2.0f * rd(C, base + 1, f));
    }
}

// ---------------------------------------------------------------- GEMM
// A(M,K) bf16 rm, Bt(N,K) bf16 rm. 128x128 tile, BK=64, XOR bank swizzle,
// XCD swizzle. MODE 1: OutBF bf16 + fused chunk aggregates (register-only).
// MODE 2: OutF fp32 = acc + U*Dvec, nontemporal.
template <int N, int K, int MODE>
__global__ __launch_bounds__(256) void gemm_bt(
    const bf16* __restrict__ A, const bf16* __restrict__ Bt,
    bf16* __restrict__ OutBF, float* __restrict__ OutF,
    const bf16* __restrict__ U, const float* __restrict__ Dvec,
    const float2* __restrict__ lam, float2* __restrict__ aggp) {
    constexpr int NXB = N / 128;
    __shared__ alignas(16) uint8_t sA[128 * 128];   // 128 rows x 64 bf16
    __shared__ alignas(16) uint8_t sB[128 * 128];

    const int tid  = threadIdx.x;
    const int wave = tid >> 6;
    const int lane = tid & 63;
    const int bid = blockIdx.x;
    const int xr  = bid & 7;
    const int jj  = bid >> 3;
    const int bx  = jj % NXB;
    const int by  = (jj / NXB) * 8 + xr;
    const int bm  = by * 128, bn = bx * 128;
    const int wm  = (wave >> 1) * 64, wn = (wave & 1) * 64;

    floatx4 acc[4][4] = {};

    const int fr   = lane & 15;
    const int kq   = lane >> 4;        // 0..3
    const int srow = tid >> 3;
    const int skc  = tid & 7;

    for (int k0 = 0; k0 < K; k0 += 64) {
        #pragma unroll
        for (int q = 0; q < 4; ++q) {
            const int row = q * 32 + srow;
            const int kcg = skc ^ (row & 7);
            gld_lds16(A  + (size_t)(bm + row) * K + k0 + kcg * 8,
                      sA + q * 4096 + wave * 1024);
            gld_lds16(Bt + (size_t)(bn + row) * K + k0 + kcg * 8,
                      sB + q * 4096 + wave * 1024);
        }
        __syncthreads();
        #pragma unroll
        for (int s = 0; s < 2; ++s) {
            bf16x8 af[4], bfr[4];
            #pragma unroll
            for (int mi = 0; mi < 4; ++mi) {
                const int row = wm + mi * 16 + fr;
                const int ch  = (s * 4 + kq) ^ (row & 7);
                af[mi] = *(const bf16x8*)(sA + row * 128 + ch * 16);
            }
            #pragma unroll
            for (int ni = 0; ni < 4; ++ni) {
                const int row = wn + ni * 16 + fr;
                const int ch  = (s * 4 + kq) ^ (row & 7);
                bfr[ni] = *(const bf16x8*)(sB + row * 128 + ch * 16);
            }
            #pragma unroll
            for (int mi = 0; mi < 4; ++mi)
                #pragma unroll
                for (int ni = 0; ni < 4; ++ni)
                    acc[mi][ni] = __builtin_amdgcn_mfma_f32_16x16x32_bf16(
                        af[mi], bfr[ni], acc[mi][ni], 0, 0, 0);
        }
        __syncthreads();
    }

    const int col0  = bn + wn + fr;
    const int rbase = bm + wm + kq * 4;
    #pragma unroll
    for (int mi = 0; mi < 4; ++mi) {
        #pragma unroll
        for (int rr = 0; rr < 4; ++rr) {
            const int row = rbase + mi * 16 + rr;
            #pragma unroll
            for (int ni = 0; ni < 4; ++ni) {
                const int c = col0 + ni * 16;
                float v = acc[mi][ni][rr];
                if (MODE == 2) {
                    float uu = __bfloat162float(U[(size_t)row * H_DIM + c]);
                    __builtin_nontemporal_store(v + uu * Dvec[c],
                                                &OutF[(size_t)row * N + c]);
                } else {
                    OutBF[(size_t)row * N + c] = __float2bfloat16(v);
                }
            }
        }
    }

    if (MODE == 1) {
        // ---- fused phase1: agg_cg(p) = sum_t lam_p^(63-t) * Bu_t(p) ----
        // Register-only weights: t = mi*16 + kq*4 + rr; iterate t descending,
        // w = lam^(63-t) starts at lam^(12-4kq), *= lam per step, *= lam^12
        // between mi groups. Even lane holds re, odd lane im (interleaved).
        const int par = fr & 1;
        const int cg  = (bm + wm) >> 6;         // global chunk of this wave
        #pragma unroll
        for (int ni = 0; ni < 4; ++ni) {
            const int ql = (wn + ni * 16 + (fr & ~1)) >> 1;   // 0..63
            const float2 lb = lam[(bn >> 1) + ql];
            const float l1r = lb.x, l1i = lb.y;
            const float l2r = l1r * l1r - l1i * l1i, l2i = 2.f * l1r * l1i;
            const float l4r = l2r * l2r - l2i * l2i, l4i = 2.f * l2r * l2i;
            const float l8r = l4r * l4r - l4i * l4i, l8i = 2.f * l4r * l4i;
            const float l12r = l8r * l4r - l8i * l4i;
            const float l12i = l8r * l4i + l8i * l4r;
            float wr_, wi_;                     // lam^(12-4kq)
            if      (kq == 0) { wr_ = l12r; wi_ = l12i; }
            else if (kq == 1) { wr_ = l8r;  wi_ = l8i;  }
            else if (kq == 2) { wr_ = l4r;  wi_ = l4i;  }
            else              { wr_ = 1.f;  wi_ = 0.f;  }
            float s = 0.f;
            #pragma unroll
            for (int mi = 3; mi >= 0; --mi) {
                #pragma unroll
                for (int rr = 3; rr >= 0; --rr) {
                    float own  = acc[mi][ni][rr];
                    float part = __shfl_xor(own, 1);
                    s += wr_ * own + (par ? wi_ : -wi_) * part;
                    float nr = wr_ * l1r - wi_ * l1i;
                    float nI = wr_ * l1i + wi_ * l1r;
                    wr_ = nr; wi_ = nI;
                }
                float nr = wr_ * l12r - wi_ * l12i;
                float nI = wr_ * l12i + wi_ * l12r;
                wr_ = nr; wi_ = nI;
            }
            s += __shfl_xor(s, 16);             // reduce over kq
            s += __shfl_xor(s, 32);
            float other = __shfl_xor(s, 1);     // partner component
            if (kq == 0 && par == 0)
                aggp[(size_t)cg * P_DIM + (bn >> 1) + ql] = make_float2(s, other);
        }
    }
}

// ---------------------------------------------------------------- scan
// phase2: wave-parallel carries. 1 wave per state; lane j owns chunks 4j..4j+3.
__global__ void scan_phase2p(const float2* __restrict__ agg,
                             const float2* __restrict__ lamT,
                             float2* __restrict__ carry) {
    const int w = threadIdx.x >> 6;
    const int j = threadIdx.x & 63;
    const int p = blockIdx.x * 4 + w;
    const float2 A = lamT[p];                               // lam^64
    float b2r = A.x * A.x - A.y * A.y, b2i = 2.f * A.x * A.y;
    float Br = b2r * b2r - b2i * b2i, Bi = 2.f * b2r * b2i; // lam^256
    float2 a[4];
    #pragma unroll
    for (int k = 0; k < 4; ++k) a[k] = agg[(size_t)(4 * j + k) * P_DIM + p];
    float xr = 0.f, xi = 0.f;
    #pragma unroll
    for (int k = 0; k < 4; ++k) {
        float nr = A.x * xr - A.y * xi + a[k].x;
        float ni = A.x * xi + A.y * xr + a[k].y;
        xr = nr; xi = ni;
    }
    float cr = Br, ci = Bi, vr = xr, vi = xi;
    #pragma unroll
    for (int d = 1; d < 64; d <<= 1) {
        float pvr = __shfl_up(vr, d), pvi = __shfl_up(vi, d);
        float pcr = __shfl_up(cr, d), pci = __shfl_up(ci, d);
        if (j >= d) {
            float nvr = cr * pvr - ci * pvi + vr;
            float nvi = cr * pvi + ci * pvr + vi;
            float ncr = cr * pcr - ci * pci;
            float nci = cr * pci + ci * pcr;
            vr = nvr; vi = nvi; cr = ncr; ci = nci;
        }
    }
    float sr = __shfl_up(vr, 1), si = __shfl_up(vi, 1);     // exclusive seed
    if (j == 0) { sr = 0.f; si = 0.f; }
    #pragma unroll
    for (int k = 0; k < 4; ++k) {
        carry[(size_t)(4 * j + k) * P_DIM + p] = make_float2(sr, si);
        float nr = A.x * sr - A.y * si + a[k].x;
        float ni = A.x * si + A.y * sr + a[k].y;
        sr = nr; si = ni;
    }
}

__global__ void scan_phase3(uint32_t* __restrict__ BuX,             // in-place
                            const float2* __restrict__ lam,
                            const float2* __restrict__ carry) {
    const int p = blockIdx.y * 256 + threadIdx.x;
    const int c = blockIdx.x;
    const float2 lb = lam[p];
    const float2 c0 = carry[(size_t)c * P_DIM + p];
    float xr = c0.x, xi = c0.y;
    uint32_t* b = BuX + (size_t)c * TCH * P_DIM + p;
    #pragma unroll 4
    for (int j = 0; j < TCH; ++j) {
        uint32_t v = *b;
        float nr = lb.x * xr - lb.y * xi + lo_bf(v);
        float ni = lb.x * xi + lb.y * xr + hi_bf(v);
        xr = nr; xi = ni;
        *b = pack_bf(xr, xi);
        b += P_DIM;
    }
}

// ---------------------------------------------------------------- launch
extern "C" void kernel_launch(void* const* d_in, const int* in_sizes, int n_in,
                              void* d_out, int out_size, void* d_ws, size_t ws_size,
                              hipStream_t stream) {
    float* out = (float*)d_out;  // (L,H) fp32

    char* w = (char*)d_ws;
    w += 256;
    float2* lam   = (float2*)w;  w += (size_t)P_DIM * 8;
    float2* lamT  = (float2*)w;  w += (size_t)P_DIM * 8;
    float*  d_f   = (float*)w;   w += (size_t)H_DIM * 4;
    float2* agg   = (float2*)w;  w += (size_t)NCH * P_DIM * 8;       // 2 MB
    float2* carry = (float2*)w;  w += (size_t)NCH * P_DIM * 8;       // 2 MB
    bf16*   W1t   = (bf16*)w;    w += (size_t)2 * P_DIM * H_DIM * 2; // 4 MB
    bf16*   W2t   = (bf16*)w;    w += (size_t)H_DIM * 2 * P_DIM * 2; // 4 MB
    bf16*   ub    = (bf16*)w;    w += (size_t)L_SEQ * H_DIM * 2;     // 33.5 MB
    bf16*   Xbuf  = (bf16*)w;                                        // 67 MB

    convert_u<<<(L_SEQ * H_DIM / 8) / 256, 256, 0, stream>>>(d_in[0], ub);
    prep_all<<<P_DIM, 256, 0, stream>>>(d_in[0], d_in[1], d_in[2], d_in[6],
                                        d_in[3], d_in[4], d_in[5],
                                        W1t, W2t, d_f, lam, lamT);

    // Bu(L,2P) = ub @ W1t^T  (interleaved cols) + fused chunk aggregates
    gemm_bt<2 * P_DIM, H_DIM, 1><<<(2 * P_DIM / 128) * 128, 256, 0, stream>>>(
        ub, W1t, Xbuf, nullptr, nullptr, nullptr, lam, agg);

    scan_phase2p<<<P_DIM / 4, 256, 0, stream>>>(agg, lamT, carry);
    scan_phase3<<<dim3(NCH, P_DIM / 256), 256, 0, stream>>>(
        (uint32_t*)Xbuf, lam, carry);

    // out = X @ W2t^T + ub*D
    gemm_bt<H_DIM, 2 * P_DIM, 2><<<(H_DIM / 128) * 128, 256, 0, stream>>>(
        Xbuf, W2t, nullptr, out, ub, d_f, nullptr, nullptr);
}